// Round 1
// baseline (67236.194 us; speedup 1.0000x reference)
//
#include <hip/hip_runtime.h>
#include <math.h>

// ---------------------------------------------------------------------------
// VRNN on MI355X — round 1 of this session.
// Key change vs previous: the recurrence is independent per batch row, so the
// scan needs NO grid barriers. 16 WGs x 16 rows each scan all 200 steps
// privately; h/A/E/z/pz live in swizzled LDS + registers; weights stay
// L2-resident (no fences -> no L2 writeback/invalidate per step).
//   * Batched pre-pass:  PX = phi_x(x); PRE_ENC = PX@enc_w1[:512]+b1;
//                        GXPX = PX@gru_w_ih[:512]+b_ih (fp32, if ws fits)
//   * Persistent per-row scan (this file's scan_k), 7 __syncthreads/step.
//   * Batched post-pass: prior chain (+kld), decoder chain. (pz written by scan)
// All GEMMs: bf16 MFMA 16x16x32, fp32 accum, weights pre-transposed to [N][K].
// ---------------------------------------------------------------------------

#define NWG 16
#define TT 200
#define BB 256
#define HD 512
#define TB (TT*BB)   // 51200

typedef unsigned short u16;
typedef __attribute__((ext_vector_type(8))) short bf16x8;
typedef __attribute__((ext_vector_type(4))) float f32x4;

// output layout (fp32, concatenated flat): z, logits, em, es, pm, ps, kld
constexpr size_t OFF_Z      = 0;
constexpr size_t OFF_LOGITS = 3276800;
constexpr size_t OFF_EM     = 16384000;
constexpr size_t OFF_ES     = 19660800;
constexpr size_t OFF_PM     = 22937600;
constexpr size_t OFF_PS     = 26214400;
constexpr size_t OFF_KLD    = 29491200;

__device__ __forceinline__ u16 f2bf(float f) {
  union { float f; unsigned u; } v; v.f = f;
  return (u16)((v.u + 0x7fffu + ((v.u >> 16) & 1u)) >> 16);  // RNE
}
__device__ __forceinline__ float bf2f(u16 b) {
  union { unsigned u; float f; } v; v.u = ((unsigned)b) << 16; return v.f;
}
__device__ __forceinline__ float sp_(float x) { return (x > 15.f) ? x : log1pf(expf(x)); }
__device__ __forceinline__ float sigm_(float x) { return 1.f / (1.f + __expf(-x)); }
// tanh via fast exp; saturates correctly at +/-inf.
__device__ __forceinline__ float tanh_(float x) { return 1.f - 2.f / (1.f + __expf(2.f * x)); }

#define MFMA(a,b,c) __builtin_amdgcn_mfma_f32_16x16x32_bf16((a),(b),(c),0,0,0)

// LDS XOR-swizzle (G4): [16][512] bf16 tiles, row stride 1024B; 16B-granular
// XOR spreads the 16 rows of a ds_read_b128 column-slice across banks.
#define SWZ(row, cb)  (((row) << 10) + ((cb) ^ (((row) & 7) << 4)))
// [16][64] bf16 tile, row stride 128B
#define SWZZ(row, cb) (((row) << 7)  + ((cb) ^ (((row) & 7) << 4)))

// ---------------------------------------------------------------------------
// weight cast+transpose: dst[c*R + r] = bf16(src[r*C + c])   (dst is [C][R])
// ---------------------------------------------------------------------------
#define NSEG 18
struct CastSeg { const float* src; u16* dst; int R; int C; };
struct CastArgs { CastSeg seg[NSEG]; };

__global__ __launch_bounds__(256) void cast_all(CastArgs a) {
  int idx = blockIdx.x * 256 + threadIdx.x;
  #pragma unroll 1
  for (int s = 0; s < NSEG; s++) {
    const int R = a.seg[s].R, C = a.seg[s].C;
    const int sz = R * C;
    if (idx < sz) {
      const int r = idx / C, c = idx - r * C;
      a.seg[s].dst[(size_t)c * R + r] = f2bf(a.seg[s].src[idx]);
      return;
    }
    idx -= sz;
  }
}

__global__ __launch_bounds__(256) void init_k(u16* H0) {
  const int i = blockIdx.x * 256 + threadIdx.x;
  if (i < BB * HD) H0[i] = 0;
}

// ---------------------------------------------------------------------------
// generic batched GEMM:  out = act( A1@Bt1^T [+ A2@Bt2^T] + bias )
// A1: [TB][K1] (bf16, or fp32 if a1f32), Bt: [N][K] bf16 (pre-transposed).
// WG = 64x64 tile, wave v -> rows +16v. M fixed = TB.
// ---------------------------------------------------------------------------
struct GB {
  const void* A1; int lda1, K1, a1f32;
  const u16* Bt1;
  const u16* A2; int lda2, K2;
  const u16* Bt2;
  const float* bias;
  u16* outB; float* outF; int ldc;
  int tilesN; int act;   // act: 0 none, 1 relu
};

__device__ __forceinline__ bf16x8 load_a8(const void* A, int f32, size_t row, int lda, int k) {
  if (!f32) return *(const bf16x8*)((const u16*)A + row * (size_t)lda + k);
  const float* p = (const float*)A + row * (size_t)lda + k;
  f32x4 x0 = *(const f32x4*)p;
  f32x4 x1 = *(const f32x4*)(p + 4);
  bf16x8 r;
  r[0]=(short)f2bf(x0[0]); r[1]=(short)f2bf(x0[1]); r[2]=(short)f2bf(x0[2]); r[3]=(short)f2bf(x0[3]);
  r[4]=(short)f2bf(x1[0]); r[5]=(short)f2bf(x1[1]); r[6]=(short)f2bf(x1[2]); r[7]=(short)f2bf(x1[3]);
  return r;
}

__global__ __launch_bounds__(256) void gemm_bt(GB g) {
  const int tn = blockIdx.x % g.tilesN, tm = blockIdx.x / g.tilesN;
  const int m0 = tm * 64, n0 = tn * 64;
  const int v = threadIdx.x >> 6, l = threadIdx.x & 63, lm = l & 15, q = l >> 4;
  const size_t rowA = m0 + v * 16 + lm;
  f32x4 acc[4] = {};
  for (int k0 = 0; k0 < g.K1; k0 += 32) {
    bf16x8 a = load_a8(g.A1, g.a1f32, rowA, g.lda1, k0 + q * 8);
    #pragma unroll
    for (int c = 0; c < 4; c++) {
      bf16x8 b = *(const bf16x8*)(g.Bt1 + (size_t)(n0 + c * 16 + lm) * g.K1 + k0 + q * 8);
      acc[c] = MFMA(a, b, acc[c]);
    }
  }
  if (g.A2) {
    for (int k0 = 0; k0 < g.K2; k0 += 32) {
      bf16x8 a = *(const bf16x8*)(g.A2 + rowA * (size_t)g.lda2 + k0 + q * 8);
      #pragma unroll
      for (int c = 0; c < 4; c++) {
        bf16x8 b = *(const bf16x8*)(g.Bt2 + (size_t)(n0 + c * 16 + lm) * g.K2 + k0 + q * 8);
        acc[c] = MFMA(a, b, acc[c]);
      }
    }
  }
  #pragma unroll
  for (int c = 0; c < 4; c++) {
    const int col = n0 + c * 16 + lm;
    const float bs = g.bias ? g.bias[col] : 0.f;
    #pragma unroll
    for (int r = 0; r < 4; r++) {
      const size_t row = (size_t)m0 + v * 16 + q * 4 + r;
      float x = acc[c][r] + bs;
      if (g.act == 1) x = fmaxf(x, 0.f);
      if (g.outB) g.outB[row * g.ldc + col] = f2bf(x);
      if (g.outF) g.outF[row * g.ldc + col] = x;
    }
  }
}

// ---------------------------------------------------------------------------
// prior mean/std heads + kld, fused.  PR:[TB][512] bf16, pms_t:[128][512]
// rows 0..63 = prior_mean cols, 64..127 = prior_std cols.
// ---------------------------------------------------------------------------
__global__ __launch_bounds__(256) void pms_kld(const u16* PR, const u16* pms_t,
                                               const float* pmb, const float* psb,
                                               float* out) {
  const int m0 = blockIdx.x * 64;
  const int v = threadIdx.x >> 6, l = threadIdx.x & 63, lm = l & 15, q = l >> 4;
  const size_t rowA = m0 + v * 16 + lm;
  f32x4 acc[8] = {};
  for (int k0 = 0; k0 < 512; k0 += 32) {
    bf16x8 a = *(const bf16x8*)(PR + rowA * 512 + k0 + q * 8);
    #pragma unroll
    for (int c = 0; c < 8; c++) {
      bf16x8 b = *(const bf16x8*)(pms_t + (size_t)(c * 16 + lm) * 512 + k0 + q * 8);
      acc[c] = MFMA(a, b, acc[c]);
    }
  }
  #pragma unroll
  for (int c = 0; c < 4; c++) {
    const int colz = c * 16 + lm;
    #pragma unroll
    for (int r = 0; r < 4; r++) {
      const size_t row = (size_t)m0 + v * 16 + q * 4 + r;
      const float pm = acc[c][r] + pmb[colz];
      const float ps = sp_(acc[c + 4][r] + psb[colz]);
      const size_t oi = row * 64 + colz;
      const float em = out[OFF_EM + oi], es = out[OFF_ES + oi];
      const float d = em - pm;
      const float kld = 0.5f * (2.f * logf(ps) - 2.f * logf(es)
                                + (es * es + d * d) / (ps * ps) - 1.f);
      out[OFF_PM + oi] = pm;
      out[OFF_PS + oi] = ps;
      out[OFF_KLD + oi] = kld;
    }
  }
}

// ---------------------------------------------------------------------------
// per-row-group scan kernel: 16 WGs, each owns 16 batch rows for all T steps.
// No grid barriers. 4 waves/WG (1 wave/SIMD -> up to 512 regs available).
// Wave w owns output cols [w*128, (w+1)*128) of every GEMM.
// ---------------------------------------------------------------------------
struct SC {
  const u16 *pre_enc, *px;
  u16 *H;
  u16 *pz_out;            // == BUF0 (same memory as pre_enc; per-step t slice
                          //  is read (P1) before being overwritten (P3c))
  const float *gxpx;      // precomputed px@gru_w_ih_top + b_ih, fp32 [TB][1536]; may be null
  const u16 *enc_w1_h_t, *enc_w2_t, *ems_t, *phi_z_t, *gru_hh_t, *gru_ih_pz_t, *gru_ih_px_t;
  const float *enc_b2, *enc_mean_b, *enc_std_b, *phi_z_b, *gru_b_ih, *gru_b_hh;
  const float *eps;
  float *out;
};

__global__ __launch_bounds__(256, 1) void scan_k(SC s) {
  const int r0 = blockIdx.x * 16;                  // this WG's batch rows
  const int w = threadIdx.x >> 6, l = threadIdx.x & 63, lm = l & 15, q = l >> 4;
  const int c0 = w * 128;                          // this wave's col base

  __shared__ u16 h16[16 * 512];    // h (bf16, swizzled) — GEMM A-operand
  __shared__ u16 Abuf[16 * 512];   // A (P1->P2), then pz (P3c->P4)
  __shared__ u16 Ebuf[16 * 512];
  __shared__ u16 zbuf[16 * 64];
  __shared__ float emsbuf[16 * 128];

  for (int i = threadIdx.x; i < 16 * 512; i += 256) h16[i] = 0;
  float hreg[32];                                  // fp32 h, cols c0..c0+128: [ct][r]
  #pragma unroll
  for (int i = 0; i < 32; i++) hreg[i] = 0.f;
  __syncthreads();

  #pragma unroll 1
  for (int t = 0; t < TT; t++) {
    // prefetch eps for P3b (issue early; ~5000cy of cover)
    float ev[4];
    #pragma unroll
    for (int i = 0; i < 4; i++) {
      const int e = threadIdx.x + i * 256;
      ev[i] = s.eps[((size_t)t * BB + r0 + (e >> 6)) * 64 + (e & 63)];
    }

    // ---- P1: A = relu(pre_enc[t] + h @ enc_w1_h) ----
    {
      const u16* pre = s.pre_enc + (size_t)t * (BB * HD);
      u16 pr[8][4];                                // prefetch before K-loop
      #pragma unroll
      for (int ct = 0; ct < 8; ct++)
        #pragma unroll
        for (int r = 0; r < 4; r++)
          pr[ct][r] = pre[(size_t)(r0 + q * 4 + r) * 512 + c0 + ct * 16 + lm];
      f32x4 acc[8] = {};
      for (int k0 = 0; k0 < 512; k0 += 32) {
        bf16x8 a = *(const bf16x8*)((const char*)h16 + SWZ(lm, (k0 + q * 8) * 2));
        #pragma unroll
        for (int ct = 0; ct < 8; ct++) {
          bf16x8 b = *(const bf16x8*)(s.enc_w1_h_t + (size_t)(c0 + ct * 16 + lm) * 512 + k0 + q * 8);
          acc[ct] = MFMA(a, b, acc[ct]);
        }
      }
      #pragma unroll
      for (int ct = 0; ct < 8; ct++) {
        const int col = c0 + ct * 16 + lm;
        #pragma unroll
        for (int r = 0; r < 4; r++) {
          const int row = q * 4 + r;
          const float x = acc[ct][r] + bf2f(pr[ct][r]);
          *(u16*)((char*)Abuf + SWZ(row, col * 2)) = f2bf(fmaxf(x, 0.f));
        }
      }
    }
    __syncthreads();

    // ---- P2: E = relu(A @ enc_w2 + b2) ----
    {
      f32x4 acc[8] = {};
      for (int k0 = 0; k0 < 512; k0 += 32) {
        bf16x8 a = *(const bf16x8*)((const char*)Abuf + SWZ(lm, (k0 + q * 8) * 2));
        #pragma unroll
        for (int ct = 0; ct < 8; ct++) {
          bf16x8 b = *(const bf16x8*)(s.enc_w2_t + (size_t)(c0 + ct * 16 + lm) * 512 + k0 + q * 8);
          acc[ct] = MFMA(a, b, acc[ct]);
        }
      }
      #pragma unroll
      for (int ct = 0; ct < 8; ct++) {
        const int col = c0 + ct * 16 + lm;
        const float bs = s.enc_b2[col];
        #pragma unroll
        for (int r = 0; r < 4; r++) {
          const int row = q * 4 + r;
          *(u16*)((char*)Ebuf + SWZ(row, col * 2)) = f2bf(fmaxf(acc[ct][r] + bs, 0.f));
        }
      }
    }
    __syncthreads();

    // ---- P3a: ems = E @ ems_t (+bias) -> emsbuf (fp32). wave w: cols w*32..+32 ----
    {
      f32x4 acc[2] = {};
      const int cb = w * 32;
      for (int k0 = 0; k0 < 512; k0 += 32) {
        bf16x8 a = *(const bf16x8*)((const char*)Ebuf + SWZ(lm, (k0 + q * 8) * 2));
        #pragma unroll
        for (int ct = 0; ct < 2; ct++) {
          bf16x8 b = *(const bf16x8*)(s.ems_t + (size_t)(cb + ct * 16 + lm) * 512 + k0 + q * 8);
          acc[ct] = MFMA(a, b, acc[ct]);
        }
      }
      #pragma unroll
      for (int ct = 0; ct < 2; ct++) {
        const int col = cb + ct * 16 + lm;
        const float bs = (col < 64) ? s.enc_mean_b[col] : s.enc_std_b[col - 64];
        #pragma unroll
        for (int r = 0; r < 4; r++)
          emsbuf[(q * 4 + r) * 128 + col] = acc[ct][r] + bs;
      }
    }
    __syncthreads();

    // ---- P3b: z = eps*sp(es)+em; write z/em/es outputs + zbuf ----
    {
      #pragma unroll
      for (int i = 0; i < 4; i++) {
        const int e = threadIdx.x + i * 256;       // 16 rows x 64 cols
        const int rr = e >> 6, cc = e & 63;
        const float em = emsbuf[rr * 128 + cc];
        const float es = sp_(emsbuf[rr * 128 + 64 + cc]);
        const size_t oi = ((size_t)t * BB + r0 + rr) * 64 + cc;
        const float z = ev[i] * es + em;
        s.out[OFF_Z + oi]  = z;
        s.out[OFF_EM + oi] = em;
        s.out[OFF_ES + oi] = es;
        *(u16*)((char*)zbuf + SWZZ(rr, cc * 2)) = f2bf(z);
      }
    }
    __syncthreads();

    // ---- P3c: pz = relu(z @ phi_z + b) -> Abuf (LDS) + BUF0 (global, for dec) ----
    {
      f32x4 acc[8] = {};
      #pragma unroll
      for (int k0 = 0; k0 < 64; k0 += 32) {
        bf16x8 a = *(const bf16x8*)((const char*)zbuf + SWZZ(lm, (k0 + q * 8) * 2));
        #pragma unroll
        for (int ct = 0; ct < 8; ct++) {
          bf16x8 b = *(const bf16x8*)(s.phi_z_t + (size_t)(c0 + ct * 16 + lm) * 64 + k0 + q * 8);
          acc[ct] = MFMA(a, b, acc[ct]);
        }
      }
      u16* pzg = s.pz_out + (size_t)t * (BB * HD);
      #pragma unroll
      for (int ct = 0; ct < 8; ct++) {
        const int col = c0 + ct * 16 + lm;
        const float bs = s.phi_z_b[col];
        #pragma unroll
        for (int r = 0; r < 4; r++) {
          const int row = q * 4 + r;
          const u16 v = f2bf(fmaxf(acc[ct][r] + bs, 0.f));
          *(u16*)((char*)Abuf + SWZ(row, col * 2)) = v;
          pzg[(size_t)(r0 + row) * 512 + col] = v;
        }
      }
    }
    __syncthreads();

    // ---- P4: gx = GXPX + pz@gru_w_ih_bot; gh = h@gru_w_hh; GRU update ----
    {
      f32x4 aIH[3][8] = {};
      f32x4 aHH[3][8] = {};
      if (s.gxpx) {
        for (int k0 = 0; k0 < 512; k0 += 32) {
          bf16x8 ah = *(const bf16x8*)((const char*)h16  + SWZ(lm, (k0 + q * 8) * 2));
          bf16x8 ap = *(const bf16x8*)((const char*)Abuf + SWZ(lm, (k0 + q * 8) * 2));
          #pragma unroll
          for (int g = 0; g < 3; g++) {
            #pragma unroll
            for (int ct = 0; ct < 8; ct++) {
              const size_t br = ((size_t)(g * 512 + c0 + ct * 16 + lm)) * 512 + k0 + q * 8;
              aIH[g][ct] = MFMA(ap, *(const bf16x8*)(s.gru_ih_pz_t + br), aIH[g][ct]);
              aHH[g][ct] = MFMA(ah, *(const bf16x8*)(s.gru_hh_t   + br), aHH[g][ct]);
            }
          }
        }
      } else {
        const u16* px_t = s.px + (size_t)t * (BB * HD);
        for (int k0 = 0; k0 < 512; k0 += 32) {
          bf16x8 ah = *(const bf16x8*)((const char*)h16  + SWZ(lm, (k0 + q * 8) * 2));
          bf16x8 ap = *(const bf16x8*)((const char*)Abuf + SWZ(lm, (k0 + q * 8) * 2));
          bf16x8 ax = *(const bf16x8*)(px_t + (size_t)(r0 + lm) * 512 + k0 + q * 8);
          #pragma unroll
          for (int g = 0; g < 3; g++) {
            #pragma unroll
            for (int ct = 0; ct < 8; ct++) {
              const size_t br = ((size_t)(g * 512 + c0 + ct * 16 + lm)) * 512 + k0 + q * 8;
              aIH[g][ct] = MFMA(ax, *(const bf16x8*)(s.gru_ih_px_t + br), aIH[g][ct]);
              aIH[g][ct] = MFMA(ap, *(const bf16x8*)(s.gru_ih_pz_t + br), aIH[g][ct]);
              aHH[g][ct] = MFMA(ah, *(const bf16x8*)(s.gru_hh_t   + br), aHH[g][ct]);
            }
          }
        }
      }
      __syncthreads();   // all waves done reading h16/Abuf before h16 overwrite

      const float* gx = s.gxpx ? (s.gxpx + ((size_t)t * BB + r0) * 1536) : nullptr;
      u16* Hn = (t < TT - 1) ? (s.H + (size_t)(t + 1) * (BB * HD)) : nullptr;
      #pragma unroll
      for (int ct = 0; ct < 8; ct++) {
        const int j = c0 + ct * 16 + lm;
        #pragma unroll
        for (int r = 0; r < 4; r++) {
          const int row = q * 4 + r;
          float xr = aIH[0][ct][r], xz = aIH[1][ct][r], xn = aIH[2][ct][r];
          if (gx) {
            xr += gx[(size_t)row * 1536 + j];
            xz += gx[(size_t)row * 1536 + 512 + j];
            xn += gx[(size_t)row * 1536 + 1024 + j];
          } else {
            xr += s.gru_b_ih[j];
            xz += s.gru_b_ih[512 + j];
            xn += s.gru_b_ih[1024 + j];
          }
          const float hr = aHH[0][ct][r] + s.gru_b_hh[j];
          const float hz = aHH[1][ct][r] + s.gru_b_hh[512 + j];
          const float hn = aHH[2][ct][r] + s.gru_b_hh[1024 + j];
          const float rg = sigm_(xr + hr);
          const float uu = sigm_(xz + hz);
          const float nn = tanh_(xn + rg * hn);
          const float hnew = (1.f - uu) * nn + uu * hreg[ct * 4 + r];
          hreg[ct * 4 + r] = hnew;
          const u16 hb = f2bf(hnew);
          *(u16*)((char*)h16 + SWZ(row, j * 2)) = hb;
          if (Hn) Hn[(size_t)(r0 + row) * 512 + j] = hb;
        }
      }
    }
    __syncthreads();   // h16 ready for next step's P1
  }
}

// ---------------------------------------------------------------------------
extern "C" void kernel_launch(void* const* d_in, const int* in_sizes, int n_in,
                              void* d_out, int out_size, void* d_ws, size_t ws_size,
                              hipStream_t stream) {
  (void)in_sizes; (void)n_in; (void)out_size;
  char* ws = (char*)d_ws;
  float* out = (float*)d_out;
  auto in = [&](int i) { return (const float*)d_in[i]; };

  size_t o = 0;
  auto take = [&](size_t bytes) { size_t r = o; o += (bytes + 255) & ~(size_t)255; return r; };
  const size_t oPhiXW1  = take(512 * 128 * 2);
  const size_t oPhiXW2  = take(512 * 512 * 2);
  const size_t oEncW1px = take(512 * 512 * 2);
  const size_t oEncW1h  = take(512 * 512 * 2);
  const size_t oEncW2   = take(512 * 512 * 2);
  const size_t oEms     = take(128 * 512 * 2);
  const size_t oPhiZ    = take(512 * 64 * 2);
  const size_t oPriorW  = take(512 * 512 * 2);
  const size_t oPriorMs = take(128 * 512 * 2);
  const size_t oDecW1pz = take(512 * 512 * 2);
  const size_t oDecW1h  = take(512 * 512 * 2);
  const size_t oDecW2   = take(512 * 512 * 2);
  const size_t oDecLog  = take(256 * 512 * 2);
  const size_t oGruIhPx = take((size_t)1536 * 512 * 2);
  const size_t oGruIhPz = take((size_t)1536 * 512 * 2);
  const size_t oGruHh   = take((size_t)1536 * 512 * 2);
  const size_t oBuf0    = take((size_t)TB * 512 * 2);
  const size_t oBuf1    = take((size_t)TB * 512 * 2);
  const size_t oH       = take((size_t)TB * 512 * 2);

  // optional fp32 GXPX = px@gru_w_ih[:512] + b_ih, precomputed batched.
  // Only if the workspace is big enough; otherwise scan computes it in-line.
  const size_t gxBytes = (size_t)TB * 1536 * 4;
  bool use_gxpx = (o + gxBytes + 4096) <= ws_size;
  size_t oGXPX = 0;
  if (use_gxpx) oGXPX = take(gxBytes);

  auto W = [&](size_t off) { return (u16*)(ws + off); };
  u16* BUF0 = W(oBuf0);
  u16* BUF1 = W(oBuf1);
  u16* Hbuf = W(oH);
  float* GXPX = use_gxpx ? (float*)(ws + oGXPX) : nullptr;

  // --- weight cast+transpose (one kernel, 18 segments) ---
  CastArgs ca;
  int si = 0;
  auto seg = [&](const float* src, u16* dst, int R, int C) { ca.seg[si++] = {src, dst, R, C}; };
  seg(in(2), W(oPhiXW1), 128, 512);
  seg(in(4), W(oPhiXW2), 512, 512);
  seg(in(8), W(oEncW1px), 512, 512);
  seg(in(8) + 512 * 512, W(oEncW1h), 512, 512);
  seg(in(10), W(oEncW2), 512, 512);
  seg(in(12), W(oEms), 512, 64);
  seg(in(14), W(oEms) + 64 * 512, 512, 64);
  seg(in(6), W(oPhiZ), 64, 512);
  seg(in(16), W(oPriorW), 512, 512);
  seg(in(18), W(oPriorMs), 512, 64);
  seg(in(20), W(oPriorMs) + 64 * 512, 512, 64);
  seg(in(22), W(oDecW1pz), 512, 512);
  seg(in(22) + 512 * 512, W(oDecW1h), 512, 512);
  seg(in(24), W(oDecW2), 512, 512);
  seg(in(26), W(oDecLog), 512, 256);
  seg(in(28), W(oGruIhPx), 512, 1536);
  seg(in(28) + 512 * 1536, W(oGruIhPz), 512, 1536);
  seg(in(30), W(oGruHh), 512, 1536);
  hipLaunchKernelGGL(cast_all, dim3(18816), dim3(256), 0, stream, ca);
  hipLaunchKernelGGL(init_k, dim3(512), dim3(256), 0, stream, Hbuf);

  auto gemm = [&](const void* A1, int lda1, int K1, int a1f32, const u16* Bt1,
                  const u16* A2, int lda2, int K2, const u16* Bt2,
                  const float* bias, u16* outB, float* outF, int ldc, int N, int act) {
    GB g;
    g.A1 = A1; g.lda1 = lda1; g.K1 = K1; g.a1f32 = a1f32; g.Bt1 = Bt1;
    g.A2 = A2; g.lda2 = lda2; g.K2 = K2; g.Bt2 = Bt2;
    g.bias = bias; g.outB = outB; g.outF = outF; g.ldc = ldc;
    g.tilesN = N / 64; g.act = act;
    hipLaunchKernelGGL(gemm_bt, dim3((TB / 64) * (N / 64)), dim3(256), 0, stream, g);
  };

  // --- pre-pass ---
  // PX1 = relu(x @ phi_x_w1 + b1)          -> BUF0
  gemm(in(0), 128, 128, 1, W(oPhiXW1), nullptr, 0, 0, nullptr, in(3), BUF0, nullptr, 512, 512, 1);
  // PX  = relu(PX1 @ phi_x_w2 + b2)        -> BUF1
  gemm(BUF0, 512, 512, 0, W(oPhiXW2), nullptr, 0, 0, nullptr, in(5), BUF1, nullptr, 512, 512, 1);
  // PRE_ENC = PX @ enc_w1[:512] + enc_b1   -> BUF0
  gemm(BUF1, 512, 512, 0, W(oEncW1px), nullptr, 0, 0, nullptr, in(9), BUF0, nullptr, 512, 512, 0);
  // GXPX = PX @ gru_w_ih[:512] + b_ih      -> fp32 (optional)
  if (use_gxpx)
    gemm(BUF1, 512, 512, 0, W(oGruIhPx), nullptr, 0, 0, nullptr, in(29), nullptr, GXPX, 1536, 1536, 0);

  // --- sequential scan (barrier-free, 16 independent row-groups) ---
  SC sc;
  sc.pre_enc = BUF0; sc.px = BUF1;
  sc.H = Hbuf; sc.pz_out = BUF0; sc.gxpx = GXPX;
  sc.enc_w1_h_t = W(oEncW1h); sc.enc_w2_t = W(oEncW2); sc.ems_t = W(oEms);
  sc.phi_z_t = W(oPhiZ); sc.gru_hh_t = W(oGruHh);
  sc.gru_ih_pz_t = W(oGruIhPz); sc.gru_ih_px_t = W(oGruIhPx);
  sc.enc_b2 = in(11); sc.enc_mean_b = in(13); sc.enc_std_b = in(15);
  sc.phi_z_b = in(7); sc.gru_b_ih = in(29); sc.gru_b_hh = in(31);
  sc.eps = in(1); sc.out = out;
  hipLaunchKernelGGL(scan_k, dim3(NWG), dim3(256), 0, stream, sc);

  // --- post-pass (batched over all T; BUF0 now holds PZ written by scan) ---
  // PR = relu(Hprev @ prior_w + b)         -> BUF1
  gemm(Hbuf, 512, 512, 0, W(oPriorW), nullptr, 0, 0, nullptr, in(17), BUF1, nullptr, 512, 512, 1);
  // pm/ps/kld                              -> d_out
  hipLaunchKernelGGL(pms_kld, dim3(TB / 64), dim3(256), 0, stream,
                     BUF1, W(oPriorMs), in(19), in(21), out);
  // DH1 = relu(PZ@dec_w1[:512] + Hprev@dec_w1[512:] + b1) -> BUF1
  gemm(BUF0, 512, 512, 0, W(oDecW1pz), Hbuf, 512, 512, W(oDecW1h), in(23), BUF1, nullptr, 512, 512, 1);
  // D = relu(DH1 @ dec_w2 + b2)            -> BUF0
  gemm(BUF1, 512, 512, 0, W(oDecW2), nullptr, 0, 0, nullptr, in(25), BUF0, nullptr, 512, 512, 1);
  // logits = D @ dec_logits + b            -> d_out fp32
  gemm(BUF0, 512, 512, 0, W(oDecLog), nullptr, 0, 0, nullptr, in(27), nullptr, out + OFF_LOGITS, 256, 256, 0);
}

// Round 2
// 34086.227 us; speedup vs baseline: 1.9725x; 1.9725x over previous
//
#include <hip/hip_runtime.h>
#include <math.h>

// ---------------------------------------------------------------------------
// VRNN on MI355X — round 2.
// Round-1 failed because 16 row-partitioned WGs streamed the full 4.25MB
// weight set from global per step (L2/L3 thrash, 16 latency-bound CUs).
// Round-2 inverts the partition: 32 WGs each hold a fixed COLUMN slice of all
// scan weights in LDS (128KiB, staged once, immune to barrier fences), and
// activations round-trip L2/L3 between 5 grid-barriered phases per step:
//   Ph1: A = relu(pre_enc + h@enc_w1_h)   [WG 0..15]   + GH = h@gru_hh+b [16..31]
//   Ph2: E = relu(A@enc_w2 + b2)          [WG 16..31]
//   Ph3: em/es = E@ems(+b); z; out writes [WG 0..3]
//   Ph4: pz = relu(z@phi_z + b)           [WG 0..15]
//   Ph5: gx = gxpx16 + pz@gru_ih_pz; GRU  [WG 0..15]  (gate triple per WG)
// GXPX = px@gru_w_ih[:512]+b_ih precomputed batched, stored fp16 (157MB).
// All GEMMs: bf16 MFMA 16x16x32, fp32 accum, weights pre-transposed to [N][K].
// ---------------------------------------------------------------------------

#define NWG 32
#define TT 200
#define BB 256
#define HD 512
#define TB (TT*BB)   // 51200

typedef unsigned short u16;
typedef _Float16 f16;
typedef __attribute__((ext_vector_type(8))) short bf16x8;
typedef __attribute__((ext_vector_type(4))) float f32x4;

// output layout (fp32, concatenated flat): z, logits, em, es, pm, ps, kld
constexpr size_t OFF_Z      = 0;
constexpr size_t OFF_LOGITS = 3276800;
constexpr size_t OFF_EM     = 16384000;
constexpr size_t OFF_ES     = 19660800;
constexpr size_t OFF_PM     = 22937600;
constexpr size_t OFF_PS     = 26214400;
constexpr size_t OFF_KLD    = 29491200;

__device__ __forceinline__ u16 f2bf(float f) {
  union { float f; unsigned u; } v; v.f = f;
  return (u16)((v.u + 0x7fffu + ((v.u >> 16) & 1u)) >> 16);  // RNE
}
__device__ __forceinline__ float bf2f(u16 b) {
  union { unsigned u; float f; } v; v.u = ((unsigned)b) << 16; return v.f;
}
__device__ __forceinline__ float sp_(float x) { return (x > 15.f) ? x : log1pf(expf(x)); }
__device__ __forceinline__ float sigm_(float x) { return 1.f / (1.f + __expf(-x)); }
__device__ __forceinline__ float tanh_(float x) { return 1.f - 2.f / (1.f + __expf(2.f * x)); }

#define MFMA(a,b,c) __builtin_amdgcn_mfma_f32_16x16x32_bf16((a),(b),(c),0,0,0)

// LDS XOR-swizzle for [row][512] bf16 weight slices (row stride 1024B):
// 16 lanes read 16 consecutive rows at the same k -> without swizzle all hit
// bank 0 (32-way). XOR of (row&7) into the 16B-chunk index spreads to 8 chunks
// (2-way residual = free on CDNA4).
#define SWZ(row, cb)  (((row) << 10) + ((cb) ^ (((row) & 7) << 4)))

// ---------------------------------------------------------------------------
// weight cast+transpose: dst[c*R + r] = bf16(src[r*C + c])   (dst is [C][R])
// ---------------------------------------------------------------------------
#define NSEG 18
struct CastSeg { const float* src; u16* dst; int R; int C; };
struct CastArgs { CastSeg seg[NSEG]; };

__global__ __launch_bounds__(256) void cast_all(CastArgs a) {
  int idx = blockIdx.x * 256 + threadIdx.x;
  #pragma unroll 1
  for (int s = 0; s < NSEG; s++) {
    const int R = a.seg[s].R, C = a.seg[s].C;
    const int sz = R * C;
    if (idx < sz) {
      const int r = idx / C, c = idx - r * C;
      a.seg[s].dst[(size_t)c * R + r] = f2bf(a.seg[s].src[idx]);
      return;
    }
    idx -= sz;
  }
}

__global__ __launch_bounds__(256) void init_k(float* h_cur, u16* H0, unsigned* sync) {
  const int i = blockIdx.x * 256 + threadIdx.x;
  if (i < BB * HD) { h_cur[i] = 0.f; H0[i] = 0; }
  if (i < 2052) sync[i] = 0u;
}

// ---------------------------------------------------------------------------
// generic batched GEMM:  out = act( A1@Bt1^T [+ A2@Bt2^T] + bias )
// ---------------------------------------------------------------------------
struct GB {
  const void* A1; int lda1, K1, a1f32;
  const u16* Bt1;
  const u16* A2; int lda2, K2;
  const u16* Bt2;
  const float* bias;
  u16* outB; float* outF; f16* outH; int ldc;
  int tilesN; int act;   // act: 0 none, 1 relu
};

__device__ __forceinline__ bf16x8 load_a8(const void* A, int f32, size_t row, int lda, int k) {
  if (!f32) return *(const bf16x8*)((const u16*)A + row * (size_t)lda + k);
  const float* p = (const float*)A + row * (size_t)lda + k;
  f32x4 x0 = *(const f32x4*)p;
  f32x4 x1 = *(const f32x4*)(p + 4);
  bf16x8 r;
  r[0]=(short)f2bf(x0[0]); r[1]=(short)f2bf(x0[1]); r[2]=(short)f2bf(x0[2]); r[3]=(short)f2bf(x0[3]);
  r[4]=(short)f2bf(x1[0]); r[5]=(short)f2bf(x1[1]); r[6]=(short)f2bf(x1[2]); r[7]=(short)f2bf(x1[3]);
  return r;
}

__global__ __launch_bounds__(256) void gemm_bt(GB g) {
  const int tn = blockIdx.x % g.tilesN, tm = blockIdx.x / g.tilesN;
  const int m0 = tm * 64, n0 = tn * 64;
  const int v = threadIdx.x >> 6, l = threadIdx.x & 63, lm = l & 15, q = l >> 4;
  const size_t rowA = m0 + v * 16 + lm;
  f32x4 acc[4] = {};
  for (int k0 = 0; k0 < g.K1; k0 += 32) {
    bf16x8 a = load_a8(g.A1, g.a1f32, rowA, g.lda1, k0 + q * 8);
    #pragma unroll
    for (int c = 0; c < 4; c++) {
      bf16x8 b = *(const bf16x8*)(g.Bt1 + (size_t)(n0 + c * 16 + lm) * g.K1 + k0 + q * 8);
      acc[c] = MFMA(a, b, acc[c]);
    }
  }
  if (g.A2) {
    for (int k0 = 0; k0 < g.K2; k0 += 32) {
      bf16x8 a = *(const bf16x8*)(g.A2 + rowA * (size_t)g.lda2 + k0 + q * 8);
      #pragma unroll
      for (int c = 0; c < 4; c++) {
        bf16x8 b = *(const bf16x8*)(g.Bt2 + (size_t)(n0 + c * 16 + lm) * g.K2 + k0 + q * 8);
        acc[c] = MFMA(a, b, acc[c]);
      }
    }
  }
  #pragma unroll
  for (int c = 0; c < 4; c++) {
    const int col = n0 + c * 16 + lm;
    const float bs = g.bias ? g.bias[col] : 0.f;
    #pragma unroll
    for (int r = 0; r < 4; r++) {
      const size_t row = (size_t)m0 + v * 16 + q * 4 + r;
      float x = acc[c][r] + bs;
      if (g.act == 1) x = fmaxf(x, 0.f);
      if (g.outB) g.outB[row * g.ldc + col] = f2bf(x);
      if (g.outF) g.outF[row * g.ldc + col] = x;
      if (g.outH) g.outH[row * g.ldc + col] = (f16)x;
    }
  }
}

// ---------------------------------------------------------------------------
// prior mean/std heads + kld, fused (post-pass).
// ---------------------------------------------------------------------------
__global__ __launch_bounds__(256) void pms_kld(const u16* PR, const u16* pms_t,
                                               const float* pmb, const float* psb,
                                               float* out) {
  const int m0 = blockIdx.x * 64;
  const int v = threadIdx.x >> 6, l = threadIdx.x & 63, lm = l & 15, q = l >> 4;
  const size_t rowA = m0 + v * 16 + lm;
  f32x4 acc[8] = {};
  for (int k0 = 0; k0 < 512; k0 += 32) {
    bf16x8 a = *(const bf16x8*)(PR + rowA * 512 + k0 + q * 8);
    #pragma unroll
    for (int c = 0; c < 8; c++) {
      bf16x8 b = *(const bf16x8*)(pms_t + (size_t)(c * 16 + lm) * 512 + k0 + q * 8);
      acc[c] = MFMA(a, b, acc[c]);
    }
  }
  #pragma unroll
  for (int c = 0; c < 4; c++) {
    const int colz = c * 16 + lm;
    #pragma unroll
    for (int r = 0; r < 4; r++) {
      const size_t row = (size_t)m0 + v * 16 + q * 4 + r;
      const float pm = acc[c][r] + pmb[colz];
      const float ps = sp_(acc[c + 4][r] + psb[colz]);
      const size_t oi = row * 64 + colz;
      const float em = out[OFF_EM + oi], es = out[OFF_ES + oi];
      const float d = em - pm;
      const float kld = 0.5f * (2.f * logf(ps) - 2.f * logf(es)
                                + (es * es + d * d) / (ps * ps) - 1.f);
      out[OFF_PM + oi] = pm;
      out[OFF_PS + oi] = ps;
      out[OFF_KLD + oi] = kld;
    }
  }
}

// ---------------------------------------------------------------------------
// persistent scan kernel: 32 WGs, column-partitioned weights in LDS.
// ---------------------------------------------------------------------------
struct SC {
  const u16 *pre_enc;     // BUF0, [TT][256][512] bf16 (slice t read in Ph1)
  u16 *pz_out;            // == BUF0 (slice t overwritten with pz in Ph4)
  u16 *H;                 // [(TT+1)][256][512] bf16; H[t] = h entering step t
  float *h_cur;           // [256][512] fp32 carry
  u16 *Abuf, *Ebuf, *zb;  // step scratch bf16: [256][512],[256][512],[256][64]
  float *GH;              // [256][1536] fp32 step scratch (h@gru_hh + b_hh)
  const f16 *gx;          // [TB][1536] fp16: px@gru_w_ih[:512] + b_ih
  const u16 *enc_w1_h_t, *enc_w2_t, *ems_t, *phi_z_t, *gru_hh_t, *gru_ih_pz_t;
  const float *enc_b2, *enc_mean_b, *enc_std_b, *phi_z_b, *gru_b_hh;
  const float *eps;
  float *out;
  unsigned *flags, *gen;
};

// two-level grid barrier (proven in the round-0 kernel; agent-scope fences).
// Weights live in LDS so the acquire-invalidate does NOT evict them.
__device__ __forceinline__ void gridbar(unsigned* flags, unsigned* gen, unsigned ticket) {
  __syncthreads();
  if (threadIdx.x == 0) {
    __threadfence();   // release: push our global writes to device scope
    __hip_atomic_store(&flags[(size_t)blockIdx.x * 32], ticket,
                       __ATOMIC_RELAXED, __HIP_MEMORY_SCOPE_AGENT);
  }
  if (blockIdx.x == 0) {
    if (threadIdx.x < NWG) {
      while (__hip_atomic_load(&flags[(size_t)threadIdx.x * 32],
                               __ATOMIC_RELAXED, __HIP_MEMORY_SCOPE_AGENT) < ticket) {}
    }
    __syncthreads();
    if (threadIdx.x == 0) {
      __threadfence();
      __hip_atomic_store(gen, ticket, __ATOMIC_RELEASE, __HIP_MEMORY_SCOPE_AGENT);
    }
  }
  if (threadIdx.x == 0) {
    while (__hip_atomic_load(gen, __ATOMIC_RELAXED, __HIP_MEMORY_SCOPE_AGENT) < ticket) {
      __builtin_amdgcn_s_sleep(1);
    }
    __threadfence();   // acquire: invalidate caches so we see others' writes
  }
  __syncthreads();
}

__global__ __launch_bounds__(256, 1) void scan_k(SC s) {
  const int w = blockIdx.x;
  const int tid = threadIdx.x;
  const int v = tid >> 6, l = tid & 63, lm = l & 15, q = l >> 4;

  // 128KiB of weight slices, swizzled. Layout (local rows of 512 bf16):
  //  w<16 : [0..32)=enc_w1_h cols[32w..32w+32); [32..128)=gru_ih_pz gate-triple
  //  w>=16: [0..96)=gru_hh gate-triple;         [96..128)=enc_w2 cols[32ww..)
  __shared__ u16 wlds[65536];

  {
    const int ww = (w < 16) ? w : w - 16;
    const u16* srcs[4];
    if (w < 16) {
      srcs[0] = s.enc_w1_h_t  + (size_t)(32 * ww) * 512;
      srcs[1] = s.gru_ih_pz_t + (size_t)(32 * ww) * 512;
      srcs[2] = s.gru_ih_pz_t + (size_t)(512 + 32 * ww) * 512;
      srcs[3] = s.gru_ih_pz_t + (size_t)(1024 + 32 * ww) * 512;
    } else {
      srcs[0] = s.gru_hh_t + (size_t)(32 * ww) * 512;
      srcs[1] = s.gru_hh_t + (size_t)(512 + 32 * ww) * 512;
      srcs[2] = s.gru_hh_t + (size_t)(1024 + 32 * ww) * 512;
      srcs[3] = s.enc_w2_t + (size_t)(32 * ww) * 512;
    }
    #pragma unroll 1
    for (int rg = 0; rg < 4; rg++) {
      const u16* sp = srcs[rg];
      const int r0 = rg * 32;
      for (int idx = tid; idx < 32 * 512; idx += 256) {
        const int lr = idx >> 9, k = idx & 511;
        *(u16*)((char*)wlds + SWZ(r0 + lr, k * 2)) = sp[(size_t)lr * 512 + k];
      }
    }
  }
  __syncthreads();

  #define LB(lr, kk) (*(const bf16x8*)((const char*)wlds + SWZ((lr), (kk) * 2)))

  #pragma unroll 1
  for (int t = 0; t < TT; t++) {
    // ================= Ph1: A [w<16] / GH [w>=16] =================
    {
      const u16* Ht = s.H + (size_t)t * (BB * HD);
      if (w < 16) {
        const u16* pre = s.pre_enc + (size_t)t * (BB * HD);
        u16 pr[2][4][4];
        #pragma unroll
        for (int ct = 0; ct < 2; ct++)
          #pragma unroll
          for (int rt = 0; rt < 4; rt++)
            #pragma unroll
            for (int r = 0; r < 4; r++)
              pr[ct][rt][r] = pre[(size_t)(v * 64 + rt * 16 + q * 4 + r) * 512
                                  + 32 * w + ct * 16 + lm];
        f32x4 acc[4][2] = {};
        for (int k0 = 0; k0 < 512; k0 += 32) {
          const bf16x8 b0 = LB(lm, k0 + q * 8);
          const bf16x8 b1 = LB(16 + lm, k0 + q * 8);
          #pragma unroll
          for (int rt = 0; rt < 4; rt++) {
            bf16x8 a = *(const bf16x8*)(Ht + (size_t)(v * 64 + rt * 16 + lm) * 512 + k0 + q * 8);
            acc[rt][0] = MFMA(a, b0, acc[rt][0]);
            acc[rt][1] = MFMA(a, b1, acc[rt][1]);
          }
        }
        #pragma unroll
        for (int ct = 0; ct < 2; ct++) {
          const int col = 32 * w + ct * 16 + lm;
          #pragma unroll
          for (int rt = 0; rt < 4; rt++)
            #pragma unroll
            for (int r = 0; r < 4; r++) {
              const int row = v * 64 + rt * 16 + q * 4 + r;
              const float x = acc[rt][ct][r] + bf2f(pr[ct][rt][r]);
              s.Abuf[(size_t)row * 512 + col] = f2bf(fmaxf(x, 0.f));
            }
        }
      } else {
        const int ww = w - 16;
        float bs[6];
        #pragma unroll
        for (int g = 0; g < 3; g++)
          #pragma unroll
          for (int sub = 0; sub < 2; sub++)
            bs[g * 2 + sub] = s.gru_b_hh[g * 512 + 32 * ww + sub * 16 + lm];
        f32x4 acc[4][6] = {};
        for (int k0 = 0; k0 < 512; k0 += 32) {
          bf16x8 b[6];
          #pragma unroll
          for (int ctn = 0; ctn < 6; ctn++)
            b[ctn] = LB((ctn >> 1) * 32 + (ctn & 1) * 16 + lm, k0 + q * 8);
          #pragma unroll
          for (int rt = 0; rt < 4; rt++) {
            bf16x8 a = *(const bf16x8*)(Ht + (size_t)(v * 64 + rt * 16 + lm) * 512 + k0 + q * 8);
            #pragma unroll
            for (int ctn = 0; ctn < 6; ctn++)
              acc[rt][ctn] = MFMA(a, b[ctn], acc[rt][ctn]);
          }
        }
        #pragma unroll
        for (int ctn = 0; ctn < 6; ctn++) {
          const int col = (ctn >> 1) * 512 + 32 * ww + (ctn & 1) * 16 + lm;
          #pragma unroll
          for (int rt = 0; rt < 4; rt++)
            #pragma unroll
            for (int r = 0; r < 4; r++) {
              const int row = v * 64 + rt * 16 + q * 4 + r;
              s.GH[(size_t)row * 1536 + col] = acc[rt][ctn][r] + bs[ctn];
            }
        }
      }
    }
    gridbar(s.flags, s.gen, (unsigned)(t * 5 + 1));

    // ================= Ph2: E [w>=16] =================
    if (w >= 16) {
      const int ww = w - 16;
      f32x4 acc[4][2] = {};
      for (int k0 = 0; k0 < 512; k0 += 32) {
        const bf16x8 b0 = LB(96 + lm, k0 + q * 8);
        const bf16x8 b1 = LB(112 + lm, k0 + q * 8);
        #pragma unroll
        for (int rt = 0; rt < 4; rt++) {
          bf16x8 a = *(const bf16x8*)(s.Abuf + (size_t)(v * 64 + rt * 16 + lm) * 512 + k0 + q * 8);
          acc[rt][0] = MFMA(a, b0, acc[rt][0]);
          acc[rt][1] = MFMA(a, b1, acc[rt][1]);
        }
      }
      #pragma unroll
      for (int ct = 0; ct < 2; ct++) {
        const int col = 32 * ww + ct * 16 + lm;
        const float bsv = s.enc_b2[col];
        #pragma unroll
        for (int rt = 0; rt < 4; rt++)
          #pragma unroll
          for (int r = 0; r < 4; r++) {
            const int row = v * 64 + rt * 16 + q * 4 + r;
            s.Ebuf[(size_t)row * 512 + col] = f2bf(fmaxf(acc[rt][ct][r] + bsv, 0.f));
          }
      }
    }
    gridbar(s.flags, s.gen, (unsigned)(t * 5 + 2));

    // ================= Ph3: em/es -> z -> outputs [w<4] =================
    if (w < 4) {
      const int col = 16 * w + lm;
      const float bm = s.enc_mean_b[col], bsd = s.enc_std_b[col];
      f32x4 acc[4][2] = {};
      for (int k0 = 0; k0 < 512; k0 += 32) {
        const bf16x8 b0 = *(const bf16x8*)(s.ems_t + (size_t)(16 * w + lm) * 512 + k0 + q * 8);
        const bf16x8 b1 = *(const bf16x8*)(s.ems_t + (size_t)(64 + 16 * w + lm) * 512 + k0 + q * 8);
        #pragma unroll
        for (int rt = 0; rt < 4; rt++) {
          bf16x8 a = *(const bf16x8*)(s.Ebuf + (size_t)(v * 64 + rt * 16 + lm) * 512 + k0 + q * 8);
          acc[rt][0] = MFMA(a, b0, acc[rt][0]);
          acc[rt][1] = MFMA(a, b1, acc[rt][1]);
        }
      }
      #pragma unroll
      for (int rt = 0; rt < 4; rt++)
        #pragma unroll
        for (int r = 0; r < 4; r++) {
          const int row = v * 64 + rt * 16 + q * 4 + r;
          const float em = acc[rt][0][r] + bm;
          const float es = sp_(acc[rt][1][r] + bsd);
          const size_t oi = ((size_t)t * BB + row) * 64 + col;
          const float z = s.eps[oi] * es + em;
          s.out[OFF_Z + oi]  = z;
          s.out[OFF_EM + oi] = em;
          s.out[OFF_ES + oi] = es;
          s.zb[(size_t)row * 64 + col] = f2bf(z);
        }
    }
    gridbar(s.flags, s.gen, (unsigned)(t * 5 + 3));

    // ================= Ph4: pz = relu(z@phi_z + b) [w<16] =================
    if (w < 16) {
      f32x4 acc[4][2] = {};
      #pragma unroll
      for (int k0 = 0; k0 < 64; k0 += 32) {
        const bf16x8 b0 = *(const bf16x8*)(s.phi_z_t + (size_t)(32 * w + lm) * 64 + k0 + q * 8);
        const bf16x8 b1 = *(const bf16x8*)(s.phi_z_t + (size_t)(32 * w + 16 + lm) * 64 + k0 + q * 8);
        #pragma unroll
        for (int rt = 0; rt < 4; rt++) {
          bf16x8 a = *(const bf16x8*)(s.zb + (size_t)(v * 64 + rt * 16 + lm) * 64 + k0 + q * 8);
          acc[rt][0] = MFMA(a, b0, acc[rt][0]);
          acc[rt][1] = MFMA(a, b1, acc[rt][1]);
        }
      }
      u16* pzg = s.pz_out + (size_t)t * (BB * HD);
      #pragma unroll
      for (int ct = 0; ct < 2; ct++) {
        const int col = 32 * w + ct * 16 + lm;
        const float bsv = s.phi_z_b[col];
        #pragma unroll
        for (int rt = 0; rt < 4; rt++)
          #pragma unroll
          for (int r = 0; r < 4; r++) {
            const int row = v * 64 + rt * 16 + q * 4 + r;
            pzg[(size_t)row * 512 + col] = f2bf(fmaxf(acc[rt][ct][r] + bsv, 0.f));
          }
      }
    }
    gridbar(s.flags, s.gen, (unsigned)(t * 5 + 4));

    // ================= Ph5: gx = gx16 + pz@gru_ih_pz; GRU [w<16] ==========
    if (w < 16) {
      const u16* pz = s.pz_out + (size_t)t * (BB * HD);
      f32x4 acc[4][6] = {};
      for (int k0 = 0; k0 < 512; k0 += 32) {
        bf16x8 b[6];
        #pragma unroll
        for (int ctn = 0; ctn < 6; ctn++)
          b[ctn] = LB(32 + (ctn >> 1) * 32 + (ctn & 1) * 16 + lm, k0 + q * 8);
        #pragma unroll
        for (int rt = 0; rt < 4; rt++) {
          bf16x8 a = *(const bf16x8*)(pz + (size_t)(v * 64 + rt * 16 + lm) * 512 + k0 + q * 8);
          #pragma unroll
          for (int ctn = 0; ctn < 6; ctn++)
            acc[rt][ctn] = MFMA(a, b[ctn], acc[rt][ctn]);
        }
      }
      const f16* gxt = s.gx + (size_t)t * BB * 1536;
      u16* Hn = s.H + (size_t)(t + 1) * (BB * HD);
      #pragma unroll
      for (int sub = 0; sub < 2; sub++) {
        const int j = 32 * w + sub * 16 + lm;
        #pragma unroll
        for (int rt = 0; rt < 4; rt++)
          #pragma unroll
          for (int r = 0; r < 4; r++) {
            const int row = v * 64 + rt * 16 + q * 4 + r;
            const size_t base = (size_t)row * 1536;
            const float xr = acc[rt][0 + sub][r] + (float)gxt[base + j];
            const float xz = acc[rt][2 + sub][r] + (float)gxt[base + 512 + j];
            const float xn = acc[rt][4 + sub][r] + (float)gxt[base + 1024 + j];
            const float hr = s.GH[base + j];
            const float hz = s.GH[base + 512 + j];
            const float hn = s.GH[base + 1024 + j];
            const float rg = sigm_(xr + hr);
            const float uu = sigm_(xz + hz);
            const float nn = tanh_(xn + rg * hn);
            const float hold = s.h_cur[(size_t)row * 512 + j];
            const float hnew = (1.f - uu) * nn + uu * hold;
            s.h_cur[(size_t)row * 512 + j] = hnew;
            Hn[(size_t)row * 512 + j] = f2bf(hnew);
          }
      }
    }
    gridbar(s.flags, s.gen, (unsigned)(t * 5 + 5));
  }
  #undef LB
}

// ---------------------------------------------------------------------------
extern "C" void kernel_launch(void* const* d_in, const int* in_sizes, int n_in,
                              void* d_out, int out_size, void* d_ws, size_t ws_size,
                              hipStream_t stream) {
  (void)in_sizes; (void)n_in; (void)out_size; (void)ws_size;
  char* ws = (char*)d_ws;
  float* out = (float*)d_out;
  auto in = [&](int i) { return (const float*)d_in[i]; };

  size_t o = 0;
  auto take = [&](size_t bytes) { size_t r = o; o += (bytes + 255) & ~(size_t)255; return r; };
  const size_t oPhiXW1  = take(512 * 128 * 2);
  const size_t oPhiXW2  = take(512 * 512 * 2);
  const size_t oEncW1px = take(512 * 512 * 2);
  const size_t oEncW1h  = take(512 * 512 * 2);
  const size_t oEncW2   = take(512 * 512 * 2);
  const size_t oEms     = take(128 * 512 * 2);
  const size_t oPhiZ    = take(512 * 64 * 2);
  const size_t oPriorW  = take(512 * 512 * 2);
  const size_t oPriorMs = take(128 * 512 * 2);
  const size_t oDecW1pz = take(512 * 512 * 2);
  const size_t oDecW1h  = take(512 * 512 * 2);
  const size_t oDecW2   = take(512 * 512 * 2);
  const size_t oDecLog  = take(256 * 512 * 2);
  const size_t oGruIhPx = take((size_t)1536 * 512 * 2);
  const size_t oGruIhPz = take((size_t)1536 * 512 * 2);
  const size_t oGruHh   = take((size_t)1536 * 512 * 2);
  const size_t oBuf0    = take((size_t)TB * 512 * 2);
  const size_t oBuf1    = take((size_t)TB * 512 * 2);
  const size_t oH       = take((size_t)(TT + 1) * BB * 512 * 2);
  const size_t oHcur    = take((size_t)BB * 512 * 4);
  const size_t oAbuf    = take((size_t)BB * 512 * 2);
  const size_t oEbuf    = take((size_t)BB * 512 * 2);
  const size_t oZb      = take((size_t)BB * 64 * 2);
  const size_t oGH      = take((size_t)BB * 1536 * 4);
  const size_t oGX      = take((size_t)TB * 1536 * 2);   // fp16 gxpx
  const size_t oSync    = take(16384);

  auto W = [&](size_t off) { return (u16*)(ws + off); };
  u16* BUF0 = W(oBuf0);
  u16* BUF1 = W(oBuf1);
  u16* Hbuf = W(oH);
  float* h_cur = (float*)(ws + oHcur);
  f16* GX16 = (f16*)(ws + oGX);
  unsigned* sync = (unsigned*)(ws + oSync);

  // --- weight cast+transpose (one kernel, 18 segments) ---
  CastArgs ca;
  int si = 0;
  auto seg = [&](const float* src, u16* dst, int R, int C) { ca.seg[si++] = {src, dst, R, C}; };
  seg(in(2), W(oPhiXW1), 128, 512);
  seg(in(4), W(oPhiXW2), 512, 512);
  seg(in(8), W(oEncW1px), 512, 512);
  seg(in(8) + 512 * 512, W(oEncW1h), 512, 512);
  seg(in(10), W(oEncW2), 512, 512);
  seg(in(12), W(oEms), 512, 64);
  seg(in(14), W(oEms) + 64 * 512, 512, 64);
  seg(in(6), W(oPhiZ), 64, 512);
  seg(in(16), W(oPriorW), 512, 512);
  seg(in(18), W(oPriorMs), 512, 64);
  seg(in(20), W(oPriorMs) + 64 * 512, 512, 64);
  seg(in(22), W(oDecW1pz), 512, 512);
  seg(in(22) + 512 * 512, W(oDecW1h), 512, 512);
  seg(in(24), W(oDecW2), 512, 512);
  seg(in(26), W(oDecLog), 512, 256);
  seg(in(28), W(oGruIhPx), 512, 1536);
  seg(in(28) + 512 * 1536, W(oGruIhPz), 512, 1536);
  seg(in(30), W(oGruHh), 512, 1536);
  hipLaunchKernelGGL(cast_all, dim3(18816), dim3(256), 0, stream, ca);
  hipLaunchKernelGGL(init_k, dim3(512), dim3(256), 0, stream, h_cur, Hbuf, sync);

  auto gemm = [&](const void* A1, int lda1, int K1, int a1f32, const u16* Bt1,
                  const u16* A2, int lda2, int K2, const u16* Bt2,
                  const float* bias, u16* outB, float* outF, f16* outH,
                  int ldc, int N, int act) {
    GB g;
    g.A1 = A1; g.lda1 = lda1; g.K1 = K1; g.a1f32 = a1f32; g.Bt1 = Bt1;
    g.A2 = A2; g.lda2 = lda2; g.K2 = K2; g.Bt2 = Bt2;
    g.bias = bias; g.outB = outB; g.outF = outF; g.outH = outH; g.ldc = ldc;
    g.tilesN = N / 64; g.act = act;
    hipLaunchKernelGGL(gemm_bt, dim3((TB / 64) * (N / 64)), dim3(256), 0, stream, g);
  };

  // --- pre-pass ---
  // PX1 = relu(x @ phi_x_w1 + b1)          -> BUF0
  gemm(in(0), 128, 128, 1, W(oPhiXW1), nullptr, 0, 0, nullptr, in(3), BUF0, nullptr, nullptr, 512, 512, 1);
  // PX  = relu(PX1 @ phi_x_w2 + b2)        -> BUF1
  gemm(BUF0, 512, 512, 0, W(oPhiXW2), nullptr, 0, 0, nullptr, in(5), BUF1, nullptr, nullptr, 512, 512, 1);
  // PRE_ENC = PX @ enc_w1[:512] + enc_b1   -> BUF0
  gemm(BUF1, 512, 512, 0, W(oEncW1px), nullptr, 0, 0, nullptr, in(9), BUF0, nullptr, nullptr, 512, 512, 0);
  // GX16 = PX @ gru_w_ih[:512] + b_ih      -> fp16
  gemm(BUF1, 512, 512, 0, W(oGruIhPx), nullptr, 0, 0, nullptr, in(29), nullptr, nullptr, GX16, 1536, 1536, 0);

  // --- sequential scan (32 WGs, LDS-resident weight slices, 5 barriers/step) ---
  SC sc;
  sc.pre_enc = BUF0; sc.pz_out = BUF0;
  sc.H = Hbuf; sc.h_cur = h_cur;
  sc.Abuf = W(oAbuf); sc.Ebuf = W(oEbuf); sc.zb = W(oZb);
  sc.GH = (float*)(ws + oGH); sc.gx = GX16;
  sc.enc_w1_h_t = W(oEncW1h); sc.enc_w2_t = W(oEncW2); sc.ems_t = W(oEms);
  sc.phi_z_t = W(oPhiZ); sc.gru_hh_t = W(oGruHh); sc.gru_ih_pz_t = W(oGruIhPz);
  sc.enc_b2 = in(11); sc.enc_mean_b = in(13); sc.enc_std_b = in(15);
  sc.phi_z_b = in(7); sc.gru_b_hh = in(31);
  sc.eps = in(1); sc.out = out;
  sc.flags = sync; sc.gen = sync + 2048;
  hipLaunchKernelGGL(scan_k, dim3(NWG), dim3(256), 0, stream, sc);

  // --- post-pass (batched over all T; BUF0 now holds PZ written by scan) ---
  // PR = relu(Hprev @ prior_w + b)         -> BUF1
  gemm(Hbuf, 512, 512, 0, W(oPriorW), nullptr, 0, 0, nullptr, in(17), BUF1, nullptr, nullptr, 512, 512, 1);
  // pm/ps/kld                              -> d_out
  hipLaunchKernelGGL(pms_kld, dim3(TB / 64), dim3(256), 0, stream,
                     BUF1, W(oPriorMs), in(19), in(21), out);
  // DH1 = relu(PZ@dec_w1[:512] + Hprev@dec_w1[512:] + b1) -> BUF1
  gemm(BUF0, 512, 512, 0, W(oDecW1pz), Hbuf, 512, 512, W(oDecW1h), in(23), BUF1, nullptr, nullptr, 512, 512, 1);
  // D = relu(DH1 @ dec_w2 + b2)            -> BUF0
  gemm(BUF1, 512, 512, 0, W(oDecW2), nullptr, 0, 0, nullptr, in(25), BUF0, nullptr, nullptr, 512, 512, 1);
  // logits = D @ dec_logits + b            -> d_out fp32
  gemm(BUF0, 512, 512, 0, W(oDecLog), nullptr, 0, 0, nullptr, in(27), nullptr, out + OFF_LOGITS, nullptr, 256, 256, 0);
}